// Round 7
// baseline (11635.278 us; speedup 1.0000x reference)
//
#include <hip/hip_runtime.h>
#include <stdint.h>

#define N_STEPS 2000
#define DT_F 0.01f

typedef float f32x2 __attribute__((ext_vector_type(2)));

// tanh(x) = 1 - 2/(exp2(2x*log2e)+1): mul, exp2, add, rcp, fma = 5 VALU.
__device__ __forceinline__ float fast_tanh(float x) {
    float e = __builtin_amdgcn_exp2f(x * 2.8853900817779268f);  // e^{2x}
    float r = __builtin_amdgcn_rcpf(e + 1.0f);
    return fmaf(-2.0f, r, 1.0f);
}

// acc.{x,y} += h.{x,y} * w.{x,y} — one VOP3P instr, all-VGPR operands.
#define PKFMA(acc, hp, wp) \
    asm("v_pk_fma_f32 %0, %1, %2, %0" : "+v"(acc) : "v"(hp), "v"(wp))
// dst = h*w + c  (3-address: kills accumulator-init movs)
#define PKFMA3(dst, hp, wp, cc) \
    asm("v_pk_fma_f32 %0, %1, %2, %3" : "=v"(dst) : "v"(hp), "v"(wp), "v"(cc))
// dst = h*w + 0  (inline constant 0 as src2)
#define PKFMA0(dst, hp, wp) \
    asm("v_pk_fma_f32 %0, %1, %2, 0" : "=v"(dst) : "v"(hp), "v"(wp))

template <int CTRL>
__device__ __forceinline__ float dpp_add(float v) {
    return v + __builtin_bit_cast(float, __builtin_amdgcn_update_dpp(
                   0, __builtin_bit_cast(int, v), CTRL, 0xf, 0xf, true));
}

// Every lane gets the sum of its row of 16 (all source lanes valid).
__device__ __forceinline__ float row16_sum(float v) {
    v = dpp_add<0xB1>(v);   // quad_perm [1,0,3,2]
    v = dpp_add<0x4E>(v);   // quad_perm [2,3,0,1]
    v = dpp_add<0x124>(v);  // row_ror:4
    v = dpp_add<0x128>(v);  // row_ror:8
    return v;
}

__device__ __forceinline__ float bperm_add(float v, int addr) {
    return v + __builtin_bit_cast(float, __builtin_amdgcn_ds_bpermute(
                   addr, __builtin_bit_cast(int, v)));
}

// Sum across 64 lanes, result uniform in a VGPR (no readlane, no SGPR movs).
__device__ __forceinline__ float wave_sum_u(float v, int a16, int a32) {
    v = row16_sum(v);
    v = bperm_add(v, a16);  // + other row in 32-half
    v = bperm_add(v, a32);  // + other half
    return v;
}

__global__ __launch_bounds__(256, 4) void node_rk4_kernel(
    const float* __restrict__ y0_in,
    const float* __restrict__ W1, const float* __restrict__ B1,
    const float* __restrict__ W2, const float* __restrict__ B2,
    const float* __restrict__ W3, const float* __restrict__ B3,
    float* __restrict__ out, int batch)
{
    __shared__ __align__(16) float hl_all[4][64];

    const int tid  = threadIdx.x;
    const int lane = tid & 63;
    const int wib  = tid >> 6;                 // wave-in-block 0..3
    const int b    = blockIdx.x * 4 + wib;     // sample id
    if (b >= batch) return;

    const int j = lane;
    const float w1_0 = W1[j], w1_1 = W1[64 + j];
    const float b1v  = B1[j];
    const float w3_0 = W3[2 * j], w3_1 = W3[2 * j + 1];
    // Fold b3 into lane 0's pre-reduction term.
    const float b3l0 = (lane == 0) ? B3[0] : 0.0f;
    const float b3l1 = (lane == 0) ? B3[1] : 0.0f;
    f32x2 bcon;                                 // {B2[j], 0} — C-operand of first pk_fma
    bcon.x = B2[j];
    bcon.y = 0.0f;

    // Pin W2 column j into 32 f32x2 VGPR pairs. VOLATILE loads cannot be
    // rematerialized/sunk by LLVM -> they execute exactly once here and the
    // 64 values stay live in VGPRs for the whole time loop. (R2-R5 bug:
    // invariant global loads were remat'd inside the K-loop; VGPR_Count 44-56.)
    f32x2 w2p[32];
    {
        const volatile float* w2v = W2;
        #pragma unroll
        for (int i = 0; i < 32; ++i) {
            w2p[i].x = w2v[(2 * i) * 64 + j];
            w2p[i].y = w2v[(2 * i + 1) * 64 + j];
        }
    }

    // bpermute lane-select addresses (bytes = lane*4).
    const int a16 = ((lane ^ 16) << 2);
    const int a32 = ((lane ^ 32) << 2);

    float y0 = y0_in[2 * b + 0];
    float y1 = y0_in[2 * b + 1];

    float* outb = out + (size_t)b * (2 * (N_STEPS + 1));
    if (lane == 0) {
        reinterpret_cast<float2*>(outb)[0] = make_float2(y0, y1);
    }

    // Keep dt constants in VGPRs.
    float chdt = 0.5f * DT_F, cdt = DT_F, cdt6 = DT_F / 6.0f;
    asm("" : "+v"(chdt), "+v"(cdt), "+v"(cdt6));

    float* hl = hl_all[wib];
    const f32x2* hp2 = (const f32x2*)hl;

    // net: wave-uniform (yi0,yi1) -> wave-uniform VGPR (o0,o1); lane j owns unit j.
    auto net = [&](float yi0, float yi1, float& o0, float& o1) {
        float pre = fmaf(yi0, w1_0, fmaf(yi1, w1_1, b1v));
        float h1  = fast_tanh(pre);
        hl[lane] = h1;
        __builtin_amdgcn_wave_barrier();   // write -> read ordering (in-wave DS order)

        f32x2 acc0, acc1, acc2, acc3;
        {
            f32x2 ha = hp2[0], hb = hp2[1], hc = hp2[2], hd = hp2[3];
            PKFMA3(acc0, ha, w2p[0], bcon);
            PKFMA0(acc1, hb, w2p[1]);
            PKFMA0(acc2, hc, w2p[2]);
            PKFMA0(acc3, hd, w2p[3]);
        }
        #pragma unroll
        for (int i = 4; i < 32; i += 4) {
            f32x2 ha = hp2[i], hb = hp2[i + 1], hc = hp2[i + 2], hd = hp2[i + 3];
            PKFMA(acc0, ha, w2p[i]);
            PKFMA(acc1, hb, w2p[i + 1]);
            PKFMA(acc2, hc, w2p[i + 2]);
            PKFMA(acc3, hd, w2p[i + 3]);
        }
        __builtin_amdgcn_wave_barrier();   // reads done before next eval's write

        f32x2 s = (acc0 + acc1) + (acc2 + acc3);
        float h2 = fast_tanh(s.x + s.y);
        float p0 = fmaf(h2, w3_0, b3l0);
        float p1 = fmaf(h2, w3_1, b3l1);
        o0 = wave_sum_u(p0, a16, a32);
        o1 = wave_sum_u(p1, a16, a32);
    };

    for (int t = 1; t <= N_STEPS; ++t) {
        float k10, k11, k20, k21, k30, k31, k40, k41;
        net(y0, y1, k10, k11);
        net(fmaf(chdt, k10, y0), fmaf(chdt, k11, y1), k20, k21);
        net(fmaf(chdt, k20, y0), fmaf(chdt, k21, y1), k30, k31);
        net(fmaf(cdt,  k30, y0), fmaf(cdt,  k31, y1), k40, k41);
        float s0 = (k10 + k40) + 2.0f * (k20 + k30);
        float s1 = (k11 + k41) + 2.0f * (k21 + k31);
        y0 = fmaf(cdt6, s0, y0);
        y1 = fmaf(cdt6, s1, y1);
        if (lane == 0) {
            reinterpret_cast<float2*>(outb)[t] = make_float2(y0, y1);
        }
    }
}

extern "C" void kernel_launch(void* const* d_in, const int* in_sizes, int n_in,
                              void* d_out, int out_size, void* d_ws, size_t ws_size,
                              hipStream_t stream) {
    const float* y0 = (const float*)d_in[0];
    const float* W1 = (const float*)d_in[1];
    const float* B1 = (const float*)d_in[2];
    const float* W2 = (const float*)d_in[3];
    const float* B2 = (const float*)d_in[4];
    const float* W3 = (const float*)d_in[5];
    const float* B3 = (const float*)d_in[6];
    float* out = (float*)d_out;

    const int batch = in_sizes[0] / 2;
    const int blocks = (batch + 3) / 4;   // 4 waves (samples) per 256-thread block

    node_rk4_kernel<<<blocks, 256, 0, stream>>>(y0, W1, B1, W2, B2, W3, B3, out, batch);
}